// Round 23
// baseline (96.491 us; speedup 1.0000x reference)
//
#include <hip/hip_runtime.h>
#include <math.h>

// SS2D: B=1, D=96, H=W=96, L=9216, K=4, N=16, R=6
constexpr int cD = 96, cL = 9216, cK = 4;
constexpr int CL = 36, NCH = 256;       // 256 chunks of 36
constexpr long cDL = (long)cD * cL;
constexpr float LOG2E = 1.44269504088896f;

// ws float offsets (BC is bf16/ushort, occupies BCW floats of space)
constexpr long BCW      = (4L * cL * 32) / 2;       // ushort array in float units
constexpr long OFF_XT    = 0;                       // [96][9216] f32
constexpr long OFF_DELTA = OFF_XT    + cDL;         // [K][96][9216] f32 d-major
constexpr long OFF_BC    = OFF_DELTA + 4L*cDL;      // [K][36][256][32] bf16, B|C
constexpr long OFF_Y     = OFF_BC    + BCW;         // [K][96][9216] f32 spatial
constexpr long OFF_PG    = OFF_Y     + 4L*cDL;      // [384][256][16] -> hin
constexpr long OFF_SG    = OFF_PG    + 384L*256*16; // [384][256][16]

__device__ __forceinline__ float4 a2prep(float4 v) {
    return make_float4(-LOG2E * exp2f(LOG2E * v.x), -LOG2E * exp2f(LOG2E * v.y),
                       -LOG2E * exp2f(LOG2E * v.z), -LOG2E * exp2f(LOG2E * v.w));
}
template<int C>
__device__ __forceinline__ float qperm(float v) {
    return __int_as_float(__builtin_amdgcn_mov_dpp(__float_as_int(v), C, 0xf, 0xf, true));
}
__device__ __forceinline__ unsigned short f2bf(float f) {
    unsigned u = __float_as_uint(f);
    u = (u + 0x7FFFu + ((u >> 16) & 1u)) >> 16;
    return (unsigned short)u;
}
__device__ __forceinline__ float bf2f(unsigned short u) {
    return __uint_as_float(((unsigned)u) << 16);
}
__device__ __forceinline__ float4 ldbf4(const unsigned short* p) {
    ushort4 v = *(const ushort4*)p;
    return make_float4(bf2f(v.x), bf2f(v.y), bf2f(v.z), bf2f(v.w));
}

// ---- kT: xT[d][w*96+h] = x[d][h*96+w] --------------------------------------
__global__ __launch_bounds__(256) void kT(const float* __restrict__ x,
                                          float* __restrict__ xT) {
    __shared__ float t[32][33];
    const int h0 = blockIdx.x * 32, w0 = blockIdx.y * 32, d = blockIdx.z;
    const float* xd = x + (long)d * cL;
    float* xtd = xT + (long)d * cL;
    for (int o = threadIdx.x; o < 1024; o += 256) {
        int i = o >> 5, j = o & 31;
        t[i][j] = xd[(h0 + i) * 96 + w0 + j];
    }
    __syncthreads();
    for (int o = threadIdx.x; o < 1024; o += 256) {
        int i = o >> 5, j = o & 31;
        xtd[(w0 + i) * 96 + h0 + j] = t[j][i];
    }
}

// ---- kA: G = W_k @ src_k; delta[k][d][p] f32, BC[k][36][256][32] bf16 ------
__global__ __launch_bounds__(256) void kA(const float* __restrict__ x,
                                          const float* __restrict__ xT,
                                          const float* __restrict__ xpw,
                                          const float* __restrict__ dtw,
                                          const float* __restrict__ dtb,
                                          float* __restrict__ delta,
                                          unsigned short* __restrict__ BCu) {
    __shared__ float xs[96][64];
    __shared__ float xdbl[38][65];
    __shared__ float dtw_l[96 * 6];
    __shared__ float dtb_l[96];
    const int p0 = blockIdx.x * 64;
    const int k  = blockIdx.y;
    const int tid = threadIdx.x;
    const float* src = (k & 1) ? xT : x;

    for (int o = tid; o < 96 * 64; o += 256) {
        int dd = o >> 6, pp = o & 63;
        xs[dd][pp] = src[(long)dd * cL + p0 + pp];
    }
    for (int o = tid; o < 96 * 6; o += 256) dtw_l[o] = dtw[k * 96 * 6 + o];
    if (tid < 96) dtb_l[tid] = dtb[k * 96 + tid];
    __syncthreads();

    const int lane = tid & 63;
    const int c0 = __builtin_amdgcn_readfirstlane((tid >> 6) * 10);
    const float* wk = xpw + (long)k * 38 * 96;
    float acc[10];
    #pragma unroll
    for (int i = 0; i < 10; ++i) acc[i] = 0.f;
    #pragma unroll 4
    for (int dd = 0; dd < 96; ++dd) {
        float xv = xs[dd][lane];
        #pragma unroll
        for (int i = 0; i < 10; ++i) {
            int c = c0 + i; c = c > 37 ? 37 : c;
            acc[i] = fmaf(xv, wk[c * 96 + dd], acc[i]);
        }
    }
    #pragma unroll
    for (int i = 0; i < 10; ++i) {
        int c = c0 + i; c = c > 37 ? 37 : c;
        xdbl[c][lane] = acc[i];
    }
    __syncthreads();

    for (int o = tid; o < 64 * 16; o += 256) {
        int n = o & 15, pp = o >> 4;
        int P = p0 + pp;
        int q = (k < 2) ? P : (9215 - P);
        int ch = q / 36, j = q - ch * 36;
        long idx = (((long)k * 36 + j) * 256 + ch) * 32 + n;
        BCu[idx]      = f2bf(xdbl[6 + n][pp]);
        BCu[idx + 16] = f2bf(xdbl[22 + n][pp]);
    }
    for (int o = tid; o < 96 * 64; o += 256) {
        int dd = o >> 6, pp = o & 63;
        float s = dtb_l[dd];
        #pragma unroll
        for (int r = 0; r < 6; ++r) s = fmaf(xdbl[r][pp], dtw_l[dd * 6 + r], s);
        float sp = fmaxf(s, 0.f) + __logf(1.f + __expf(-fabsf(s)));
        delta[((long)(k * 96 + dd)) * cL + p0 + pp] = sp;
    }
}

// ---- kS1: half-seq summaries; delta/x in LDS; B bf16 -----------------------
__global__ __launch_bounds__(512, 4) void kS1(const float* __restrict__ x,
                                              const float* __restrict__ xT,
                                              const float* __restrict__ delta,
                                              const unsigned short* __restrict__ BCu,
                                              const float* __restrict__ Alog,
                                              float* __restrict__ Pg,
                                              float* __restrict__ Sg) {
    __shared__ float dls[4608], xls[4608];      // 36.9 KB
    const int tid = threadIdx.x;
    const int n0 = (tid & 3) * 4, chl = tid >> 2;   // chl in [0,128)
    const int hb = blockIdx.x & 1, seq = blockIdx.x >> 1;
    const int k = seq / 96, d = seq % 96, rev = k >> 1;
    const int ch = hb * 128 + chl;

    const float* dRow = delta + (long)seq * cL;
    const float* xRow = ((k & 1) ? xT : x) + (long)d * cL;
    const int sb2 = rev ? (1 - hb) * 4608 : hb * 4608;
    for (int o = tid; o < 1152; o += 512) {
        ((float4*)dls)[o] = ((const float4*)(dRow + sb2))[o];
        ((float4*)xls)[o] = ((const float4*)(xRow + sb2))[o];
    }
    const float4 a2 = a2prep(*(const float4*)(Alog + (long)seq * 16 + n0));
    const unsigned short* bc = BCu + ((long)k * 36 * 256 + ch) * 32 + n0;
    __syncthreads();

    const int sbase = chl * 36;
    float4 h = make_float4(0.f, 0.f, 0.f, 0.f);
    float sdl = 0.f;
#define STEP1(DL, XV, B) { \
        float t = (DL) * (XV); sdl += (DL); \
        h.x = fmaf(exp2f((DL)*a2.x), h.x, t*(B).x); \
        h.y = fmaf(exp2f((DL)*a2.y), h.y, t*(B).y); \
        h.z = fmaf(exp2f((DL)*a2.z), h.z, t*(B).z); \
        h.w = fmaf(exp2f((DL)*a2.w), h.w, t*(B).w); }
    #pragma unroll
    for (int g = 0; g < 9; ++g) {
        const unsigned short* bj = bc + (long)(4 * g) * 8192;
        float4 B0 = ldbf4(bj);
        float4 B1 = ldbf4(bj + 8192);
        float4 B2 = ldbf4(bj + 16384);
        float4 B3 = ldbf4(bj + 24576);
        float4 d4, x4;
        if (!rev) {
            d4 = *(const float4*)(dls + sbase + 4 * g);
            x4 = *(const float4*)(xls + sbase + 4 * g);
            STEP1(d4.x, x4.x, B0) STEP1(d4.y, x4.y, B1)
            STEP1(d4.z, x4.z, B2) STEP1(d4.w, x4.w, B3)
        } else {
            d4 = *(const float4*)(dls + 4604 - sbase - 4 * g);
            x4 = *(const float4*)(xls + 4604 - sbase - 4 * g);
            STEP1(d4.w, x4.w, B0) STEP1(d4.z, x4.z, B1)
            STEP1(d4.y, x4.y, B2) STEP1(d4.x, x4.x, B3)
        }
    }
#undef STEP1
    long o = ((long)seq * NCH + ch) * 16 + n0;
    *(float4*)(Pg + o) = make_float4(exp2f(a2.x*sdl), exp2f(a2.y*sdl),
                                     exp2f(a2.z*sdl), exp2f(a2.w*sdl));
    *(float4*)(Sg + o) = h;
}

// ---- kC: scan 256 summaries per seq; exclusive inits overwrite Pg ----------
__global__ __launch_bounds__(256) void kC(float* __restrict__ Pg,
                                          const float* __restrict__ Sg) {
    __shared__ float gp[256], gs[256];
    const int seq = blockIdx.x;
    const int tid = threadIdx.x;
    const int sn = tid & 15, sg = tid >> 4;          // sg in [0,16)
    const long base = (long)seq * 4096 + sg * 256 + sn;

    float LPe[16], LSe[16];
    float P = 1.f, S = 0.f;
    #pragma unroll
    for (int i = 0; i < 16; ++i) {
        float p = Pg[base + i * 16], s = Sg[base + i * 16];
        LPe[i] = P; LSe[i] = S;
        S = fmaf(p, S, s); P *= p;
    }
    gp[tid] = P; gs[tid] = S;
    __syncthreads();
    #pragma unroll
    for (int off = 1; off < 16; off <<= 1) {
        float pc = gp[tid], sc = gs[tid];
        float pn = pc, s2 = sc;
        if (sg >= off) {
            pn = pc * gp[tid - off * 16];
            s2 = fmaf(pc, gs[tid - off * 16], sc);
        }
        __syncthreads();
        gp[tid] = pn; gs[tid] = s2;
        __syncthreads();
    }
    const float GS = (sg == 0) ? 0.f : gs[tid - 16];
    #pragma unroll
    for (int i = 0; i < 16; ++i)
        Pg[base + i * 16] = fmaf(LPe[i], GS, LSe[i]);  // hin
}

// ---- kR: pure replay, quarter-seq blocks; B/C bf16; ybuf writeout ----------
__global__ __launch_bounds__(256, 4) void kR(const float* __restrict__ x,
                                             const float* __restrict__ xT,
                                             const float* __restrict__ delta,
                                             const unsigned short* __restrict__ BCu,
                                             const float* __restrict__ Alog,
                                             const float* __restrict__ Dsv,
                                             const float* __restrict__ hin,
                                             float* __restrict__ y) {
    __shared__ float dls[2304], xls[2304];
    __shared__ float ybuf[2304 + 24];
    const int tid = threadIdx.x;
    const int n0 = (tid & 3) * 4, chl = tid >> 2, r = tid & 3;  // chl [0,64)
    const int qb = blockIdx.x & 3, seq = blockIdx.x >> 2;
    const int k = seq / 96, d = seq % 96, rev = k >> 1;
    const int ch = qb * 64 + chl;

    const float* dRow = delta + (long)seq * cL;
    const float* xRow = ((k & 1) ? xT : x) + (long)d * cL;
    const int sb = rev ? (3 - qb) * 2304 : qb * 2304;    // spatial base
    for (int o = tid; o < 576; o += 256) {
        ((float4*)dls)[o] = ((const float4*)(dRow + sb))[o];
        ((float4*)xls)[o] = ((const float4*)(xRow + sb))[o];
    }
    const float4 a2 = a2prep(*(const float4*)(Alog + (long)seq * 16 + n0));
    const float Dv = Dsv[seq];
    const unsigned short* bc = BCu + ((long)k * 36 * 256 + ch) * 32 + n0;
    float4 h = *(const float4*)(hin + ((long)seq * NCH + ch) * 16 + n0);
    __syncthreads();

    const int sbase = chl * 36;
    float yhold = 0.f;
#define STEP2(DL, XV, B, C, SI) { \
        float t = (DL) * (XV); \
        h.x = fmaf(exp2f((DL)*a2.x), h.x, t*(B).x); \
        h.y = fmaf(exp2f((DL)*a2.y), h.y, t*(B).y); \
        h.z = fmaf(exp2f((DL)*a2.z), h.z, t*(B).z); \
        h.w = fmaf(exp2f((DL)*a2.w), h.w, t*(B).w); \
        float pv = fmaf(h.x, (C).x, fmaf(h.y, (C).y, fmaf(h.z, (C).z, h.w * (C).w))); \
        pv += qperm<0xB1>(pv); \
        pv += qperm<0x4E>(pv); \
        if ((SI) == r) yhold = fmaf(Dv, (XV), pv); }
    #pragma unroll
    for (int g = 0; g < 9; ++g) {
        const unsigned short* bj = bc + (long)(4 * g) * 8192;
        float4 B0 = ldbf4(bj);
        float4 C0 = ldbf4(bj + 16);
        float4 B1 = ldbf4(bj + 8192);
        float4 C1 = ldbf4(bj + 8192 + 16);
        float4 B2 = ldbf4(bj + 16384);
        float4 C2 = ldbf4(bj + 16384 + 16);
        float4 B3 = ldbf4(bj + 24576);
        float4 C3 = ldbf4(bj + 24576 + 16);
        float4 d4, x4;
        if (!rev) {
            d4 = *(const float4*)(dls + sbase + 4 * g);
            x4 = *(const float4*)(xls + sbase + 4 * g);
            STEP2(d4.x, x4.x, B0, C0, 0) STEP2(d4.y, x4.y, B1, C1, 1)
            STEP2(d4.z, x4.z, B2, C2, 2) STEP2(d4.w, x4.w, B3, C3, 3)
        } else {
            d4 = *(const float4*)(dls + 2300 - sbase - 4 * g);
            x4 = *(const float4*)(xls + 2300 - sbase - 4 * g);
            STEP2(d4.w, x4.w, B0, C0, 0) STEP2(d4.z, x4.z, B1, C1, 1)
            STEP2(d4.y, x4.y, B2, C2, 2) STEP2(d4.x, x4.x, B3, C3, 3)
        }
        int sl = sbase + 4 * g + r;
        int yloc = rev ? 2303 - sl : sl;
        ybuf[yloc + yloc / 96] = yhold;
    }
#undef STEP2
    __syncthreads();

    float* yrow = y + (long)seq * cL;
    if (k & 1) {
        const int w0 = sb / 96;
        for (int o = tid; o < 2304; o += 256) {
            int hh = o / 24, wl = o - hh * 24;
            yrow[hh * 96 + w0 + wl] = ybuf[wl * 97 + hh];
        }
    } else {
        for (int o = tid; o < 2304; o += 256) {
            yrow[sb + o] = ybuf[o + o / 96];
        }
    }
}

// ---- kE: 4-dir sum (all spatial, d-major) + LayerNorm; 32 p per block ------
__global__ __launch_bounds__(256) void kE(const float* __restrict__ y,
                                          const float* __restrict__ lnw,
                                          const float* __restrict__ lnb,
                                          float* __restrict__ out) {
    __shared__ float vs[96][36];
    __shared__ float red[8][32], red2[8][32];
    __shared__ float MU[32], RS[32];
    const int tid = threadIdx.x;
    const int p0 = blockIdx.x * 32;

    for (int o = tid; o < 96 * 8; o += 256) {
        int dd = o >> 3, j = o & 7;
        const float* r0 = y + (long)dd * cL + p0;
        const float* r1 = y + cDL + (long)dd * cL + p0;
        const float* r2 = y + 2 * cDL + (long)dd * cL + p0;
        const float* r3 = y + 3 * cDL + (long)dd * cL + p0;
        float4 a = ((const float4*)r0)[j];
        float4 b = ((const float4*)r1)[j];
        float4 c = ((const float4*)r2)[j];
        float4 e = ((const float4*)r3)[j];
        *(float4*)&vs[dd][4 * j] = make_float4(a.x + b.x + c.x + e.x,
                                               a.y + b.y + c.y + e.y,
                                               a.z + b.z + c.z + e.z,
                                               a.w + b.w + c.w + e.w);
    }
    __syncthreads();

    const int p = tid & 31, part = tid >> 5;
    float s = 0.f, s2 = 0.f;
    for (int dd = part * 12; dd < part * 12 + 12; ++dd) {
        float v = vs[dd][p];
        s += v; s2 = fmaf(v, v, s2);
    }
    red[part][p] = s; red2[part][p] = s2;
    __syncthreads();
    if (tid < 32) {
        float S = 0.f, S2 = 0.f;
        #pragma unroll
        for (int q = 0; q < 8; ++q) { S += red[q][tid]; S2 += red2[q][tid]; }
        float m = S * (1.f / 96.f);
        MU[tid] = m;
        RS[tid] = rsqrtf(S2 * (1.f / 96.f) - m * m + 1e-5f);
    }
    __syncthreads();
    for (int o = tid; o < 32 * 96; o += 256) {
        int pl = o / 96, dd = o - pl * 96;
        out[(long)(p0 + pl) * 96 + dd] = (vs[dd][pl] - MU[pl]) * RS[pl] * lnw[dd] + lnb[dd];
    }
}

extern "C" void kernel_launch(void* const* d_in, const int* in_sizes, int n_in,
                              void* d_out, int out_size, void* d_ws, size_t ws_size,
                              hipStream_t stream) {
    const float* x    = (const float*)d_in[0];
    const float* xpw  = (const float*)d_in[1];
    const float* dtw  = (const float*)d_in[2];
    const float* dtb  = (const float*)d_in[3];
    const float* Alog = (const float*)d_in[4];
    const float* Dsv  = (const float*)d_in[5];
    const float* lnw  = (const float*)d_in[6];
    const float* lnb  = (const float*)d_in[7];
    float* ws = (float*)d_ws;

    float* xT    = ws + OFF_XT;
    float* delta = ws + OFF_DELTA;
    unsigned short* BCu = (unsigned short*)(ws + OFF_BC);
    float* y     = ws + OFF_Y;
    float* Pg    = ws + OFF_PG;     // -> hin after kC
    float* Sg    = ws + OFF_SG;
    float* out   = (float*)d_out;

    kT<<<dim3(3, 3, 96), 256, 0, stream>>>(x, xT);
    kA<<<dim3(144, 4), 256, 0, stream>>>(x, xT, xpw, dtw, dtb, delta, BCu);
    kS1<<<768, 512, 0, stream>>>(x, xT, delta, BCu, Alog, Pg, Sg);
    kC<<<384, 256, 0, stream>>>(Pg, Sg);
    kR<<<1536, 256, 0, stream>>>(x, xT, delta, BCu, Alog, Dsv, Pg, y);
    kE<<<288, 256, 0, stream>>>(y, lnw, lnb, out);
}

// Round 24
// 91.992 us; speedup vs baseline: 1.0489x; 1.0489x over previous
//
#include <hip/hip_runtime.h>
#include <math.h>

// SS2D: B=1, D=96, H=W=96, L=9216, K=4, N=16, R=6
constexpr int cD = 96, cL = 9216, cK = 4;
constexpr int CL = 36, NCH = 256;       // 256 chunks of 36
constexpr long cDL = (long)cD * cL;
constexpr float LOG2E = 1.44269504088896f;

// ws float offsets
constexpr long OFF_XT    = 0;                       // [96][9216]
constexpr long OFF_DELTA = OFF_XT    + cDL;         // [K][96][9216] d-major
constexpr long OFF_BC    = OFF_DELTA + 4L*cDL;      // [K][36][256][32] j-major, B|C
constexpr long OFF_Y     = OFF_BC    + 4L*cL*32;    // [K][96][9216] spatial raster
constexpr long OFF_PG    = OFF_Y     + 4L*cDL;      // [384][256][16] -> hin
constexpr long OFF_SG    = OFF_PG    + 384L*256*16; // [384][256][16]

__device__ __forceinline__ float4 a2prep(float4 v) {
    return make_float4(-LOG2E * exp2f(LOG2E * v.x), -LOG2E * exp2f(LOG2E * v.y),
                       -LOG2E * exp2f(LOG2E * v.z), -LOG2E * exp2f(LOG2E * v.w));
}
template<int C>
__device__ __forceinline__ float qperm(float v) {
    return __int_as_float(__builtin_amdgcn_mov_dpp(__float_as_int(v), C, 0xf, 0xf, true));
}

// ---- kT: xT[d][w*96+h] = x[d][h*96+w] --------------------------------------
__global__ __launch_bounds__(256) void kT(const float* __restrict__ x,
                                          float* __restrict__ xT) {
    __shared__ float t[32][33];
    const int h0 = blockIdx.x * 32, w0 = blockIdx.y * 32, d = blockIdx.z;
    const float* xd = x + (long)d * cL;
    float* xtd = xT + (long)d * cL;
    for (int o = threadIdx.x; o < 1024; o += 256) {
        int i = o >> 5, j = o & 31;
        t[i][j] = xd[(h0 + i) * 96 + w0 + j];
    }
    __syncthreads();
    for (int o = threadIdx.x; o < 1024; o += 256) {
        int i = o >> 5, j = o & 31;
        xtd[(w0 + i) * 96 + h0 + j] = t[j][i];
    }
}

// ---- kA: G = W_k @ src_k; delta[k][d][p], BC[k][36][256][32] ---------------
__global__ __launch_bounds__(256) void kA(const float* __restrict__ x,
                                          const float* __restrict__ xT,
                                          const float* __restrict__ xpw,
                                          const float* __restrict__ dtw,
                                          const float* __restrict__ dtb,
                                          float* __restrict__ delta,
                                          float* __restrict__ BC) {
    __shared__ float xs[96][64];
    __shared__ float xdbl[38][65];
    __shared__ float dtw_l[96 * 6];
    __shared__ float dtb_l[96];
    const int p0 = blockIdx.x * 64;
    const int k  = blockIdx.y;
    const int tid = threadIdx.x;
    const float* src = (k & 1) ? xT : x;

    for (int o = tid; o < 96 * 64; o += 256) {
        int dd = o >> 6, pp = o & 63;
        xs[dd][pp] = src[(long)dd * cL + p0 + pp];
    }
    for (int o = tid; o < 96 * 6; o += 256) dtw_l[o] = dtw[k * 96 * 6 + o];
    if (tid < 96) dtb_l[tid] = dtb[k * 96 + tid];
    __syncthreads();

    const int lane = tid & 63;
    const int c0 = __builtin_amdgcn_readfirstlane((tid >> 6) * 10);
    const float* wk = xpw + (long)k * 38 * 96;
    float acc[10];
    #pragma unroll
    for (int i = 0; i < 10; ++i) acc[i] = 0.f;
    #pragma unroll 4
    for (int dd = 0; dd < 96; ++dd) {
        float xv = xs[dd][lane];
        #pragma unroll
        for (int i = 0; i < 10; ++i) {
            int c = c0 + i; c = c > 37 ? 37 : c;
            acc[i] = fmaf(xv, wk[c * 96 + dd], acc[i]);
        }
    }
    #pragma unroll
    for (int i = 0; i < 10; ++i) {
        int c = c0 + i; c = c > 37 ? 37 : c;
        xdbl[c][lane] = acc[i];
    }
    __syncthreads();

    for (int o = tid; o < 64 * 16; o += 256) {
        int n = o & 15, pp = o >> 4;
        int P = p0 + pp;
        int q = (k < 2) ? P : (9215 - P);
        int ch = q / 36, j = q - ch * 36;
        long idx = (((long)k * 36 + j) * 256 + ch) * 32 + n;
        BC[idx]      = xdbl[6 + n][pp];
        BC[idx + 16] = xdbl[22 + n][pp];
    }
    for (int o = tid; o < 96 * 64; o += 256) {
        int dd = o >> 6, pp = o & 63;
        float s = dtb_l[dd];
        #pragma unroll
        for (int r = 0; r < 6; ++r) s = fmaf(xdbl[r][pp], dtw_l[dd * 6 + r], s);
        float sp = fmaxf(s, 0.f) + __logf(1.f + __expf(-fabsf(s)));
        delta[((long)(k * 96 + dd)) * cL + p0 + pp] = sp;
    }
}

// ---- kS1: half-seq summaries; delta/x staged in LDS ------------------------
__global__ __launch_bounds__(512, 6) void kS1(const float* __restrict__ x,
                                              const float* __restrict__ xT,
                                              const float* __restrict__ delta,
                                              const float* __restrict__ BC,
                                              const float* __restrict__ Alog,
                                              float* __restrict__ Pg,
                                              float* __restrict__ Sg) {
    __shared__ float dls[4608], xls[4608];      // 36.9 KB
    const int tid = threadIdx.x;
    const int n0 = (tid & 3) * 4, chl = tid >> 2;   // chl in [0,128)
    const int hb = blockIdx.x & 1, seq = blockIdx.x >> 1;
    const int k = seq / 96, d = seq % 96, rev = k >> 1;
    const int ch = hb * 128 + chl;

    const float* dRow = delta + (long)seq * cL;
    const float* xRow = ((k & 1) ? xT : x) + (long)d * cL;
    const int sb2 = rev ? (1 - hb) * 4608 : hb * 4608;   // spatial base of range
    for (int o = tid; o < 1152; o += 512) {
        ((float4*)dls)[o] = ((const float4*)(dRow + sb2))[o];
        ((float4*)xls)[o] = ((const float4*)(xRow + sb2))[o];
    }
    const float4 a2 = a2prep(*(const float4*)(Alog + (long)seq * 16 + n0));
    const float* bc = BC + ((long)k * 36 * 256 + ch) * 32 + n0;
    __syncthreads();

    const int sbase = chl * 36;                 // local scan base within half
    float4 h = make_float4(0.f, 0.f, 0.f, 0.f);
    float sdl = 0.f;
#define STEP1(DL, XV, B) { \
        float t = (DL) * (XV); sdl += (DL); \
        h.x = fmaf(exp2f((DL)*a2.x), h.x, t*(B).x); \
        h.y = fmaf(exp2f((DL)*a2.y), h.y, t*(B).y); \
        h.z = fmaf(exp2f((DL)*a2.z), h.z, t*(B).z); \
        h.w = fmaf(exp2f((DL)*a2.w), h.w, t*(B).w); }
    #pragma unroll
    for (int g = 0; g < 9; ++g) {
        const float* bj = bc + (long)(4 * g) * 8192;
        float4 B0 = *(const float4*)(bj);
        float4 B1 = *(const float4*)(bj + 8192);
        float4 B2 = *(const float4*)(bj + 16384);
        float4 B3 = *(const float4*)(bj + 24576);
        float4 d4, x4;
        if (!rev) {
            d4 = *(const float4*)(dls + sbase + 4 * g);
            x4 = *(const float4*)(xls + sbase + 4 * g);
            STEP1(d4.x, x4.x, B0) STEP1(d4.y, x4.y, B1)
            STEP1(d4.z, x4.z, B2) STEP1(d4.w, x4.w, B3)
        } else {
            d4 = *(const float4*)(dls + 4604 - sbase - 4 * g);
            x4 = *(const float4*)(xls + 4604 - sbase - 4 * g);
            STEP1(d4.w, x4.w, B0) STEP1(d4.z, x4.z, B1)
            STEP1(d4.y, x4.y, B2) STEP1(d4.x, x4.x, B3)
        }
    }
#undef STEP1
    long o = ((long)seq * NCH + ch) * 16 + n0;
    *(float4*)(Pg + o) = make_float4(exp2f(a2.x*sdl), exp2f(a2.y*sdl),
                                     exp2f(a2.z*sdl), exp2f(a2.w*sdl));
    *(float4*)(Sg + o) = h;
}

// ---- kC: scan 256 summaries per seq; exclusive inits overwrite Pg ----------
__global__ __launch_bounds__(256) void kC(float* __restrict__ Pg,
                                          const float* __restrict__ Sg) {
    __shared__ float gp[256], gs[256];
    const int seq = blockIdx.x;
    const int tid = threadIdx.x;
    const int sn = tid & 15, sg = tid >> 4;          // sg in [0,16)
    const long base = (long)seq * 4096 + sg * 256 + sn;

    float LPe[16], LSe[16];
    float P = 1.f, S = 0.f;
    #pragma unroll
    for (int i = 0; i < 16; ++i) {
        float p = Pg[base + i * 16], s = Sg[base + i * 16];
        LPe[i] = P; LSe[i] = S;
        S = fmaf(p, S, s); P *= p;
    }
    gp[tid] = P; gs[tid] = S;
    __syncthreads();
    #pragma unroll
    for (int off = 1; off < 16; off <<= 1) {
        float pc = gp[tid], sc = gs[tid];
        float pn = pc, s2 = sc;
        if (sg >= off) {
            pn = pc * gp[tid - off * 16];
            s2 = fmaf(pc, gs[tid - off * 16], sc);
        }
        __syncthreads();
        gp[tid] = pn; gs[tid] = s2;
        __syncthreads();
    }
    const float GS = (sg == 0) ? 0.f : gs[tid - 16];
    #pragma unroll
    for (int i = 0; i < 16; ++i)
        Pg[base + i * 16] = fmaf(LPe[i], GS, LSe[i]);  // hin
}

// ---- kR: pure replay, quarter-seq blocks; delta/x staged; ybuf writeout ----
__global__ __launch_bounds__(256, 5) void kR(const float* __restrict__ x,
                                             const float* __restrict__ xT,
                                             const float* __restrict__ delta,
                                             const float* __restrict__ BC,
                                             const float* __restrict__ Alog,
                                             const float* __restrict__ Dsv,
                                             const float* __restrict__ hin,
                                             float* __restrict__ y) {
    __shared__ float dls[2304], xls[2304];
    __shared__ float ybuf[2304 + 24];
    const int tid = threadIdx.x;
    const int n0 = (tid & 3) * 4, chl = tid >> 2, r = tid & 3;  // chl [0,64)
    const int qb = blockIdx.x & 3, seq = blockIdx.x >> 2;
    const int k = seq / 96, d = seq % 96, rev = k >> 1;
    const int ch = qb * 64 + chl;

    const float* dRow = delta + (long)seq * cL;
    const float* xRow = ((k & 1) ? xT : x) + (long)d * cL;
    const int sb = rev ? (3 - qb) * 2304 : qb * 2304;    // spatial base
    for (int o = tid; o < 576; o += 256) {
        ((float4*)dls)[o] = ((const float4*)(dRow + sb))[o];
        ((float4*)xls)[o] = ((const float4*)(xRow + sb))[o];
    }
    const float4 a2 = a2prep(*(const float4*)(Alog + (long)seq * 16 + n0));
    const float Dv = Dsv[seq];
    const float* bc = BC + ((long)k * 36 * 256 + ch) * 32 + n0;
    float4 h = *(const float4*)(hin + ((long)seq * NCH + ch) * 16 + n0);
    __syncthreads();

    const int sbase = chl * 36;
    float yhold = 0.f;
#define STEP2(DL, XV, B, C, SI) { \
        float t = (DL) * (XV); \
        h.x = fmaf(exp2f((DL)*a2.x), h.x, t*(B).x); \
        h.y = fmaf(exp2f((DL)*a2.y), h.y, t*(B).y); \
        h.z = fmaf(exp2f((DL)*a2.z), h.z, t*(B).z); \
        h.w = fmaf(exp2f((DL)*a2.w), h.w, t*(B).w); \
        float pv = fmaf(h.x, (C).x, fmaf(h.y, (C).y, fmaf(h.z, (C).z, h.w * (C).w))); \
        pv += qperm<0xB1>(pv); \
        pv += qperm<0x4E>(pv); \
        if ((SI) == r) yhold = fmaf(Dv, (XV), pv); }
    #pragma unroll
    for (int g = 0; g < 9; ++g) {
        const float* bj = bc + (long)(4 * g) * 8192;
        float4 B0 = *(const float4*)(bj);
        float4 C0 = *(const float4*)(bj + 16);
        float4 B1 = *(const float4*)(bj + 8192);
        float4 C1 = *(const float4*)(bj + 8192 + 16);
        float4 B2 = *(const float4*)(bj + 16384);
        float4 C2 = *(const float4*)(bj + 16384 + 16);
        float4 B3 = *(const float4*)(bj + 24576);
        float4 C3 = *(const float4*)(bj + 24576 + 16);
        float4 d4, x4;
        if (!rev) {
            d4 = *(const float4*)(dls + sbase + 4 * g);
            x4 = *(const float4*)(xls + sbase + 4 * g);
            STEP2(d4.x, x4.x, B0, C0, 0) STEP2(d4.y, x4.y, B1, C1, 1)
            STEP2(d4.z, x4.z, B2, C2, 2) STEP2(d4.w, x4.w, B3, C3, 3)
        } else {
            d4 = *(const float4*)(dls + 2300 - sbase - 4 * g);
            x4 = *(const float4*)(xls + 2300 - sbase - 4 * g);
            STEP2(d4.w, x4.w, B0, C0, 0) STEP2(d4.z, x4.z, B1, C1, 1)
            STEP2(d4.y, x4.y, B2, C2, 2) STEP2(d4.x, x4.x, B3, C3, 3)
        }
        int sl = sbase + 4 * g + r;
        int yloc = rev ? 2303 - sl : sl;
        ybuf[yloc + yloc / 96] = yhold;
    }
#undef STEP2
    __syncthreads();

    float* yrow = y + (long)seq * cL;
    if (k & 1) {
        const int w0 = sb / 96;
        for (int o = tid; o < 2304; o += 256) {
            int hh = o / 24, wl = o - hh * 24;
            yrow[hh * 96 + w0 + wl] = ybuf[wl * 97 + hh];
        }
    } else {
        for (int o = tid; o < 2304; o += 256) {
            yrow[sb + o] = ybuf[o + o / 96];
        }
    }
}

// ---- kE: 4-dir sum (all spatial, d-major) + LayerNorm; 32 p per block ------
__global__ __launch_bounds__(256) void kE(const float* __restrict__ y,
                                          const float* __restrict__ lnw,
                                          const float* __restrict__ lnb,
                                          float* __restrict__ out) {
    __shared__ float vs[96][36];
    __shared__ float red[8][32], red2[8][32];
    __shared__ float MU[32], RS[32];
    const int tid = threadIdx.x;
    const int p0 = blockIdx.x * 32;

    for (int o = tid; o < 96 * 8; o += 256) {
        int dd = o >> 3, j = o & 7;
        const float* r0 = y + (long)dd * cL + p0;
        const float* r1 = y + cDL + (long)dd * cL + p0;
        const float* r2 = y + 2 * cDL + (long)dd * cL + p0;
        const float* r3 = y + 3 * cDL + (long)dd * cL + p0;
        float4 a = ((const float4*)r0)[j];
        float4 b = ((const float4*)r1)[j];
        float4 c = ((const float4*)r2)[j];
        float4 e = ((const float4*)r3)[j];
        *(float4*)&vs[dd][4 * j] = make_float4(a.x + b.x + c.x + e.x,
                                               a.y + b.y + c.y + e.y,
                                               a.z + b.z + c.z + e.z,
                                               a.w + b.w + c.w + e.w);
    }
    __syncthreads();

    const int p = tid & 31, part = tid >> 5;
    float s = 0.f, s2 = 0.f;
    for (int dd = part * 12; dd < part * 12 + 12; ++dd) {
        float v = vs[dd][p];
        s += v; s2 = fmaf(v, v, s2);
    }
    red[part][p] = s; red2[part][p] = s2;
    __syncthreads();
    if (tid < 32) {
        float S = 0.f, S2 = 0.f;
        #pragma unroll
        for (int q = 0; q < 8; ++q) { S += red[q][tid]; S2 += red2[q][tid]; }
        float m = S * (1.f / 96.f);
        MU[tid] = m;
        RS[tid] = rsqrtf(S2 * (1.f / 96.f) - m * m + 1e-5f);
    }
    __syncthreads();
    for (int o = tid; o < 32 * 96; o += 256) {
        int pl = o / 96, dd = o - pl * 96;
        out[(long)(p0 + pl) * 96 + dd] = (vs[dd][pl] - MU[pl]) * RS[pl] * lnw[dd] + lnb[dd];
    }
}

extern "C" void kernel_launch(void* const* d_in, const int* in_sizes, int n_in,
                              void* d_out, int out_size, void* d_ws, size_t ws_size,
                              hipStream_t stream) {
    const float* x    = (const float*)d_in[0];
    const float* xpw  = (const float*)d_in[1];
    const float* dtw  = (const float*)d_in[2];
    const float* dtb  = (const float*)d_in[3];
    const float* Alog = (const float*)d_in[4];
    const float* Dsv  = (const float*)d_in[5];
    const float* lnw  = (const float*)d_in[6];
    const float* lnb  = (const float*)d_in[7];
    float* ws = (float*)d_ws;

    float* xT    = ws + OFF_XT;
    float* delta = ws + OFF_DELTA;
    float* BC    = ws + OFF_BC;
    float* y     = ws + OFF_Y;
    float* Pg    = ws + OFF_PG;     // -> hin after kC
    float* Sg    = ws + OFF_SG;
    float* out   = (float*)d_out;

    kT<<<dim3(3, 3, 96), 256, 0, stream>>>(x, xT);
    kA<<<dim3(144, 4), 256, 0, stream>>>(x, xT, xpw, dtw, dtb, delta, BC);
    kS1<<<768, 512, 0, stream>>>(x, xT, delta, BC, Alog, Pg, Sg);
    kC<<<384, 256, 0, stream>>>(Pg, Sg);
    kR<<<1536, 256, 0, stream>>>(x, xT, delta, BC, Alog, Dsv, Pg, y);
    kE<<<288, 256, 0, stream>>>(y, lnw, lnb, out);
}